// Round 1
// baseline (1665.940 us; speedup 1.0000x reference)
//
#include <hip/hip_runtime.h>
#include <math.h>

#define NN 50000
#define NE 640000

// ---- degree -----------------------------------------------------------------
__global__ void k_deg(const int* __restrict__ dst, float* __restrict__ deg, int E) {
    int e = blockIdx.x * blockDim.x + threadIdx.x;
    if (e < E) atomicAdd(&deg[dst[e]], 1.0f);
}

__global__ void k_deginv(float* __restrict__ deg, int N) {
    int i = blockIdx.x * blockDim.x + threadIdx.x;
    if (i < N) deg[i] = 1.0f / fmaxf(deg[i], 1.0f);
}

// ---- scatter mean (sum part): one thread per (edge, channel) ----------------
template <int LOGC>
__global__ void k_scatter(const float* __restrict__ xin, const int* __restrict__ src,
                          const int* __restrict__ dst, float* __restrict__ agg,
                          long long total) {
    const int C = 1 << LOGC;
    long long idx = (long long)blockIdx.x * blockDim.x + threadIdx.x;
    if (idx >= total) return;
    int e = (int)(idx >> LOGC);
    int c = (int)(idx & (C - 1));
    float v = xin[((long long)src[e] << LOGC) + c];
    atomicAdd(&agg[((long long)dst[e] << LOGC) + c], v);
}

// ---- SAGE layer GEMM: out[i][j] = relu?( dinv[i]*sum_k agg[i][k]Wl[k][j]
//                                          + sum_k x[i][k]Wr[k][j] + b[j] ) ---
__global__ void k_sage_gemm(const float* __restrict__ agg, const float* __restrict__ xin,
                            const float* __restrict__ Wl, const float* __restrict__ Wr,
                            const float* __restrict__ b, const float* __restrict__ dinv,
                            float* __restrict__ out, int N, int Cin, int Cout, int do_relu) {
    int idx = blockIdx.x * blockDim.x + threadIdx.x;
    if (idx >= N * Cout) return;
    int i = idx / Cout;
    int j = idx - i * Cout;
    const float* arow = agg + (long long)i * Cin;
    const float* xrow = xin + (long long)i * Cin;
    float sl = 0.f, sr = 0.f;
    for (int k = 0; k < Cin; ++k) {
        sl += arow[k] * Wl[k * Cout + j];
        sr += xrow[k] * Wr[k * Cout + j];
    }
    float v = sl * dinv[i] + sr + b[j];
    if (do_relu) v = fmaxf(v, 0.f);
    out[(long long)i * Cout + j] = v;
}

// ---- classifier head: Linear(64,32)+ReLU -> Linear(32,1)+Sigmoid ------------
__global__ void k_classifier(const float* __restrict__ h, const float* __restrict__ Wc1,
                             const float* __restrict__ bc1, const float* __restrict__ Wc2,
                             const float* __restrict__ bc2, float* __restrict__ out, int N) {
    int i = blockIdx.x * blockDim.x + threadIdx.x;
    if (i >= N) return;
    float hrow[64];
#pragma unroll
    for (int k = 0; k < 64; ++k) hrow[k] = h[(long long)i * 64 + k];
    float acc = bc2[0];
    for (int j = 0; j < 32; ++j) {
        float s = bc1[j];
#pragma unroll
        for (int k = 0; k < 64; ++k) s += hrow[k] * Wc1[k * 32 + j];
        acc += fmaxf(s, 0.f) * Wc2[j];
    }
    out[i] = 1.0f / (1.0f + expf(-acc));
}

extern "C" void kernel_launch(void* const* d_in, const int* in_sizes, int n_in,
                              void* d_out, int out_size, void* d_ws, size_t ws_size,
                              hipStream_t stream) {
    const float* x   = (const float*)d_in[0];
    const int*   ei  = (const int*)d_in[1];   // [2, NE] int32 (JAX x64 disabled)
    const int*   src = ei;
    const int*   dst = ei + NE;
    const float* Wl0 = (const float*)d_in[2];
    const float* Wr0 = (const float*)d_in[3];
    const float* b0  = (const float*)d_in[4];
    const float* Wl1 = (const float*)d_in[5];
    const float* Wr1 = (const float*)d_in[6];
    const float* b1  = (const float*)d_in[7];
    const float* Wl2 = (const float*)d_in[8];
    const float* Wr2 = (const float*)d_in[9];
    const float* b2  = (const float*)d_in[10];
    const float* Wc1 = (const float*)d_in[11];
    const float* bc1 = (const float*)d_in[12];
    const float* Wc2 = (const float*)d_in[13];
    const float* bc2 = (const float*)d_in[14];
    float* out = (float*)d_out;

    // workspace layout (bytes):
    //   [0,       0.2MB) deg / deg_inv      (NN floats)
    //   [1MB,    26.6MB) agg                (NN*128 floats max)
    //   [28MB,   53.6MB) h0                 (NN*128 floats)
    //   [54MB,   79.6MB) h1                 (NN*128 floats)
    char* ws   = (char*)d_ws;
    float* deg = (float*)(ws);
    float* agg = (float*)(ws + (size_t)1 * (1 << 20));
    float* h0  = (float*)(ws + (size_t)28 * (1 << 20));
    float* h1  = (float*)(ws + (size_t)54 * (1 << 20));

    const int B = 256;

    // degree (once, reused by all 3 layers)
    hipMemsetAsync(deg, 0, (size_t)NN * sizeof(float), stream);
    k_deg<<<(NE + B - 1) / B, B, 0, stream>>>(dst, deg, NE);
    k_deginv<<<(NN + B - 1) / B, B, 0, stream>>>(deg, NN);

    // layer 0: aggregate x (C=64), GEMM K=64 -> 128, ReLU
    hipMemsetAsync(agg, 0, (size_t)NN * 64 * sizeof(float), stream);
    {
        long long T = (long long)NE * 64;
        k_scatter<6><<<(unsigned)((T + B - 1) / B), B, 0, stream>>>(x, src, dst, agg, T);
    }
    k_sage_gemm<<<(NN * 128 + B - 1) / B, B, 0, stream>>>(agg, x, Wl0, Wr0, b0, deg, h0,
                                                          NN, 64, 128, 1);

    // layer 1: aggregate h0 (C=128), GEMM K=128 -> 128, ReLU
    hipMemsetAsync(agg, 0, (size_t)NN * 128 * sizeof(float), stream);
    {
        long long T = (long long)NE * 128;
        k_scatter<7><<<(unsigned)((T + B - 1) / B), B, 0, stream>>>(h0, src, dst, agg, T);
    }
    k_sage_gemm<<<(NN * 128 + B - 1) / B, B, 0, stream>>>(agg, h0, Wl1, Wr1, b1, deg, h1,
                                                          NN, 128, 128, 1);

    // layer 2: aggregate h1 (C=128), GEMM K=128 -> 64, no ReLU (reuse h0 as h2)
    hipMemsetAsync(agg, 0, (size_t)NN * 128 * sizeof(float), stream);
    {
        long long T = (long long)NE * 128;
        k_scatter<7><<<(unsigned)((T + B - 1) / B), B, 0, stream>>>(h1, src, dst, agg, T);
    }
    k_sage_gemm<<<(NN * 64 + B - 1) / B, B, 0, stream>>>(agg, h1, Wl2, Wr2, b2, deg, h0,
                                                         NN, 128, 64, 0);

    // classifier head
    k_classifier<<<(NN + B - 1) / B, B, 0, stream>>>(h0, Wc1, bc1, Wc2, bc2, out, NN);
}